// Round 13
// baseline (268.691 us; speedup 1.0000x reference)
//
#include <hip/hip_runtime.h>
#include <hip/hip_bf16.h>
#include <stdint.h>

#define B_   4
#define T_   4096
#define HID_ 1024
#define H_   16
#define D_   64
#define CCH  64              // scan chunk length
#define NC_  (T_ / CCH)      // 64 chunks

typedef __attribute__((ext_vector_type(8))) short short8;     // 8 bf16 = 4 VGPRs
typedef __attribute__((ext_vector_type(4))) float f32x4;

__device__ __forceinline__ float phi_(float x) { return x > 0.f ? x + 1.f : __expf(x); }
__device__ __forceinline__ float sigm_(float x) { return 1.f / (1.f + expf(-x)); }

#define BAR() __builtin_amdgcn_s_barrier()
#define PRIO1() __builtin_amdgcn_s_setprio(1)
#define PRIO0() __builtin_amdgcn_s_setprio(0)
#define SCHED0() __builtin_amdgcn_sched_barrier(0)
#define WAITVM0()   { asm volatile("s_waitcnt vmcnt(0)" ::: "memory"); SCHED0(); }
#define WAITVM8()   { asm volatile("s_waitcnt vmcnt(8)" ::: "memory"); SCHED0(); }
#define WAITLGKM0() { asm volatile("s_waitcnt lgkmcnt(0)" ::: "memory"); SCHED0(); }

// ---------------- fused prep: cast x->bf16 (8/thread) + 2 weight transposes ----------
#define NB_CAST (B_ * T_ * HID_ / 2048)                 // 8192
#define NB_TQ   ((3 * HID_ / 32) * (HID_ / 32))         // 3072
#define NB_TO   ((HID_ / 32) * (2 * HID_ / 32))         // 2048
__global__ __launch_bounds__(256) void k_prep(const float* __restrict__ x,
                                              const float* __restrict__ wqkv,
                                              const float* __restrict__ wout,
                                              __hip_bfloat16* __restrict__ xb,
                                              __hip_bfloat16* __restrict__ wqkvT,
                                              __hip_bfloat16* __restrict__ woutT) {
  int bid = blockIdx.x, tid = threadIdx.x;
  if (bid < NB_CAST) {                    // ---- cast: 2048 elems/block
    size_t i = (size_t)bid * 2048 + tid * 8;
    float4 f0 = *(const float4*)(x + i);
    float4 f1 = *(const float4*)(x + i + 4);
    union { short8 v; unsigned short u[8]; } o;
    o.u[0] = __bfloat16_as_ushort(__float2bfloat16(f0.x));
    o.u[1] = __bfloat16_as_ushort(__float2bfloat16(f0.y));
    o.u[2] = __bfloat16_as_ushort(__float2bfloat16(f0.z));
    o.u[3] = __bfloat16_as_ushort(__float2bfloat16(f0.w));
    o.u[4] = __bfloat16_as_ushort(__float2bfloat16(f1.x));
    o.u[5] = __bfloat16_as_ushort(__float2bfloat16(f1.y));
    o.u[6] = __bfloat16_as_ushort(__float2bfloat16(f1.z));
    o.u[7] = __bfloat16_as_ushort(__float2bfloat16(f1.w));
    *(short8*)(xb + i) = o.v;
    return;
  }
  __shared__ float tile[32][33];
  const float* in; __hip_bfloat16* out; int R, C, tb;
  if (bid < NB_CAST + NB_TQ) { in = wqkv; out = wqkvT; R = HID_; C = 3 * HID_; tb = bid - NB_CAST; }
  else                       { in = wout; out = woutT; R = 2 * HID_; C = HID_; tb = bid - NB_CAST - NB_TQ; }
  int nbx = C / 32;
  int c0 = (tb % nbx) * 32, r0 = (tb / nbx) * 32;
  int tx = tid & 31, ty = tid >> 5;        // 32 x 8
#pragma unroll
  for (int i = 0; i < 32; i += 8)
    tile[ty + i][tx] = in[(size_t)(r0 + ty + i) * C + c0 + tx];
  __syncthreads();
#pragma unroll
  for (int i = 0; i < 32; i += 8)
    out[(size_t)(c0 + ty + i) * R + r0 + tx] = __float2bfloat16(tile[tx][ty + i]);
}

// ---------------- async global -> LDS (16B/lane; LDS base wave-uniform) ----------------
__device__ __forceinline__ void gload_lds16(const __hip_bfloat16* g, const __hip_bfloat16* lds) {
  __builtin_amdgcn_global_load_lds(
      (const __attribute__((address_space(1))) uint32_t*)(uintptr_t)g,
      (__attribute__((address_space(3))) uint32_t*)(uintptr_t)lds, 16, 0, 0);
}

// ====================== GEMM variant A (R7, best for GEMM1: K=1024) ==================
template <typename OutT>
__global__ __launch_bounds__(512, 2) void k_gemmA(const __hip_bfloat16* __restrict__ A,
                                                  const __hip_bfloat16* __restrict__ BT,
                                                  OutT* __restrict__ C,
                                                  int M, int N, int K) {
  __shared__ __hip_bfloat16 lds[65536];
  const int tid = threadIdx.x, lane = tid & 63, wid = tid >> 6;
  const int wm = wid >> 2, wn = wid & 3;
  const int r16 = lane & 15, k8 = ((lane >> 4) & 3) * 8;

  const int bid = blockIdx.x;
  const int MT = M >> 8, Rb = MT >> 3;
  const int x = bid & 7, ii = bid >> 3;
  const int rt = x * Rb + (ii % Rb), ct = ii / Rb;
  const int bm = rt << 8, bn = ct << 8;

  const int sRow = wid * 8 + (lane >> 3);
  const int sCol = ((lane & 7) * 8) ^ ((lane >> 3) << 3);
  const __hip_bfloat16* gA = A  + (size_t)(bm + sRow) * K + sCol;
  const __hip_bfloat16* gB = BT + (size_t)(bn + sRow) * K + sCol;

  auto stageA2 = [&](int buf, int kt, int half) {
#pragma unroll
    for (int cc = half * 2; cc < half * 2 + 2; ++cc)
      gload_lds16(gA + (size_t)cc * 64 * K + kt, &lds[buf * 32768 + cc * 4096 + wid * 512]);
  };
  auto stageB2 = [&](int buf, int kt, int half) {
#pragma unroll
    for (int cc = half * 2; cc < half * 2 + 2; ++cc)
      gload_lds16(gB + (size_t)cc * 64 * K + kt, &lds[buf * 32768 + 16384 + cc * 4096 + wid * 512]);
  };
  auto ldA = [&](int buf, int m, int kk) -> short8 {
    int row = wm * 128 + m * 16 + r16;
    int col = (kk * 32 + k8) ^ ((row & 7) << 3);
    return *(const short8*)&lds[buf * 32768 + (row << 6) + col];
  };
  auto ldB = [&](int buf, int n, int kk) -> short8 {
    int row = wn * 64 + n * 16 + r16;
    int col = (kk * 32 + k8) ^ ((row & 7) << 3);
    return *(const short8*)&lds[buf * 32768 + 16384 + (row << 6) + col];
  };

  f32x4 acc[8][4] = {};
  const int NT = K >> 6;

  stageA2(0, 0, 0);  stageA2(0, 0, 1);  stageB2(0, 0, 0);  stageB2(0, 0, 1);
  stageA2(1, 64, 0); stageA2(1, 64, 1); stageB2(1, 64, 0); stageB2(1, 64, 1);
  WAITVM8(); BAR();

  short8 a[8][2], bfr[4][2];
  for (int t = 0; t < NT; ++t) {
    const int cb = t & 1;
    const bool pf = (t + 2 < NT);
    const int kt2 = (t + 2) << 6;
#pragma unroll
    for (int m = 0; m < 8; ++m) { a[m][0] = ldA(cb, m, 0); a[m][1] = ldA(cb, m, 1); }
#pragma unroll
    for (int n = 0; n < 4; ++n) { bfr[n][0] = ldB(cb, n, 0); bfr[n][1] = ldB(cb, n, 1); }
    WAITLGKM0();
    BAR();
    PRIO1();
#pragma unroll
    for (int m = 0; m < 2; ++m)
#pragma unroll
      for (int n = 0; n < 4; ++n) {
        acc[m][n] = __builtin_amdgcn_mfma_f32_16x16x32_bf16(a[m][0], bfr[n][0], acc[m][n], 0, 0, 0);
        acc[m][n] = __builtin_amdgcn_mfma_f32_16x16x32_bf16(a[m][1], bfr[n][1], acc[m][n], 0, 0, 0);
      }
    PRIO0();
    if (pf) stageA2(cb, kt2, 0);
    PRIO1();
#pragma unroll
    for (int m = 2; m < 4; ++m)
#pragma unroll
      for (int n = 0; n < 4; ++n) {
        acc[m][n] = __builtin_amdgcn_mfma_f32_16x16x32_bf16(a[m][0], bfr[n][0], acc[m][n], 0, 0, 0);
        acc[m][n] = __builtin_amdgcn_mfma_f32_16x16x32_bf16(a[m][1], bfr[n][1], acc[m][n], 0, 0, 0);
      }
    PRIO0();
    if (pf) stageA2(cb, kt2, 1);
    PRIO1();
#pragma unroll
    for (int m = 4; m < 6; ++m)
#pragma unroll
      for (int n = 0; n < 4; ++n) {
        acc[m][n] = __builtin_amdgcn_mfma_f32_16x16x32_bf16(a[m][0], bfr[n][0], acc[m][n], 0, 0, 0);
        acc[m][n] = __builtin_amdgcn_mfma_f32_16x16x32_bf16(a[m][1], bfr[n][1], acc[m][n], 0, 0, 0);
      }
    PRIO0();
    if (pf) stageB2(cb, kt2, 0);
    PRIO1();
#pragma unroll
    for (int m = 6; m < 8; ++m)
#pragma unroll
      for (int n = 0; n < 4; ++n) {
        acc[m][n] = __builtin_amdgcn_mfma_f32_16x16x32_bf16(a[m][0], bfr[n][0], acc[m][n], 0, 0, 0);
        acc[m][n] = __builtin_amdgcn_mfma_f32_16x16x32_bf16(a[m][1], bfr[n][1], acc[m][n], 0, 0, 0);
      }
    PRIO0();
    if (pf)              { stageB2(cb, kt2, 1); WAITVM8(); }
    else if (t + 1 < NT) { WAITVM0(); }
    BAR();
  }

#pragma unroll
  for (int m = 0; m < 8; ++m)
#pragma unroll
    for (int n = 0; n < 4; ++n)
#pragma unroll
      for (int j = 0; j < 4; ++j) {
        int row = bm + wm * 128 + m * 16 + ((lane >> 4) << 2) + j;
        int col = bn + wn * 64 + n * 16 + r16;
        if constexpr (sizeof(OutT) == 4)
          C[(size_t)row * N + col] = acc[m][n][j];
        else
          C[(size_t)row * N + col] = __float2bfloat16(acc[m][n][j]);
      }
}

// ====================== GEMM variant B (R8 K-split, best for GEMM2: K=2048) ==========
template <typename OutT>
__global__ __launch_bounds__(512, 2) void k_gemmB(const __hip_bfloat16* __restrict__ A,
                                                  const __hip_bfloat16* __restrict__ BT,
                                                  OutT* __restrict__ C,
                                                  int M, int N, int K) {
  __shared__ __hip_bfloat16 lds[65536];
  const int tid = threadIdx.x, lane = tid & 63, wid = tid >> 6;
  const int wm = wid >> 2, wn = wid & 3;
  const int r16 = lane & 15, k8 = ((lane >> 4) & 3) * 8;

  const int bid = blockIdx.x;
  const int MT = M >> 8, Rb = MT >> 3;
  const int x = bid & 7, ii = bid >> 3;
  const int rt = x * Rb + (ii % Rb), ct = ii / Rb;
  const int bm = rt << 8, bn = ct << 8;

  const int sRow = wid * 8 + (lane >> 3);
  const int sCol = ((lane & 7) * 8) ^ ((lane >> 3) << 3);
  const __hip_bfloat16* gA = A  + (size_t)(bm + sRow) * K + sCol;
  const __hip_bfloat16* gB = BT + (size_t)(bn + sRow) * K + sCol;

  auto stage = [&](int buf, int kt) {
#pragma unroll
    for (int cc = 0; cc < 4; ++cc)
      gload_lds16(gA + (size_t)cc * 64 * K + kt, &lds[buf * 32768 + cc * 4096 + wid * 512]);
#pragma unroll
    for (int cc = 0; cc < 4; ++cc)
      gload_lds16(gB + (size_t)cc * 64 * K + kt, &lds[buf * 32768 + 16384 + cc * 4096 + wid * 512]);
  };
  auto ldA = [&](int buf, int m, int kk) -> short8 {
    int row = wm * 128 + m * 16 + r16;
    int col = (kk * 32 + k8) ^ ((row & 7) << 3);
    return *(const short8*)&lds[buf * 32768 + (row << 6) + col];
  };
  auto ldB = [&](int buf, int n, int kk) -> short8 {
    int row = wn * 64 + n * 16 + r16;
    int col = (kk * 32 + k8) ^ ((row & 7) << 3);
    return *(const short8*)&lds[buf * 32768 + 16384 + (row << 6) + col];
  };

  f32x4 acc[8][4] = {};
  const int NT = K >> 6;

  short8 A0[8], B0[4], A1[8], B1[4];
  stage(0, 0);
  stage(1, 64);
  WAITVM8(); BAR();
#pragma unroll
  for (int m = 0; m < 8; ++m) A0[m] = ldA(0, m, 0);
#pragma unroll
  for (int n = 0; n < 4; ++n) B0[n] = ldB(0, n, 0);
  SCHED0();

  for (int t = 0; t < NT; ++t) {
    const int cb = t & 1;
#pragma unroll
    for (int m = 0; m < 8; ++m) A1[m] = ldA(cb, m, 1);
#pragma unroll
    for (int n = 0; n < 4; ++n) B1[n] = ldB(cb, n, 1);
    SCHED0();
    PRIO1();
#pragma unroll
    for (int m = 0; m < 8; ++m)
#pragma unroll
      for (int n = 0; n < 4; ++n)
        acc[m][n] = __builtin_amdgcn_mfma_f32_16x16x32_bf16(A0[m], B0[n], acc[m][n], 0, 0, 0);
    PRIO0();
    WAITLGKM0();
    BAR();
    if (t + 2 < NT)      { stage(cb, (t + 2) << 6); WAITVM8(); BAR(); }
    else if (t + 1 < NT) { WAITVM0(); BAR(); }
    if (t + 1 < NT) {
#pragma unroll
      for (int m = 0; m < 8; ++m) A0[m] = ldA(cb ^ 1, m, 0);
#pragma unroll
      for (int n = 0; n < 4; ++n) B0[n] = ldB(cb ^ 1, n, 0);
      SCHED0();
    }
    PRIO1();
#pragma unroll
    for (int m = 0; m < 8; ++m)
#pragma unroll
      for (int n = 0; n < 4; ++n)
        acc[m][n] = __builtin_amdgcn_mfma_f32_16x16x32_bf16(A1[m], B1[n], acc[m][n], 0, 0, 0);
    PRIO0();
  }

#pragma unroll
  for (int m = 0; m < 8; ++m)
#pragma unroll
    for (int n = 0; n < 4; ++n)
#pragma unroll
      for (int j = 0; j < 4; ++j) {
        int row = bm + wm * 128 + m * 16 + ((lane >> 4) << 2) + j;
        int col = bn + wn * 64 + n * 16 + r16;
        if constexpr (sizeof(OutT) == 4)
          C[(size_t)row * N + col] = acc[m][n][j];
        else
          C[(size_t)row * N + col] = __float2bfloat16(acc[m][n][j]);
      }
}

// ---------------- scan phase 1: per-chunk local tails (zero init) ----------------
__global__ __launch_bounds__(64) void k_scan1(const __hip_bfloat16* __restrict__ qkv,
                                              const float* __restrict__ alpha,
                                              const float* __restrict__ beta,
                                              float* __restrict__ chunkL) {
  int blk = blockIdx.x;
  int c = blk & (NC_ - 1), h = (blk >> 6) & (H_ - 1), b = blk >> 10;
  int d = threadIdx.x;
  float da = fmaxf(sigm_(alpha[h]), 1e-8f);
  float db = fmaxf(sigm_(beta[h]), 1e-8f);
  const __hip_bfloat16* base = qkv + (size_t)(b * T_ + c * CCH) * (3 * HID_) + h * D_ + d;
  float l0 = 0.f, l1 = 0.f, l2 = 0.f, l3 = 0.f;
#pragma unroll 4
  for (int t = 0; t < CCH; ++t) {
    float k = phi_(__bfloat162float(base[HID_]));
    float v = __bfloat162float(base[2 * HID_]);
    float kv = k * v;
    l0 = da * l0 + kv; l1 = da * l1 + k;
    l2 = db * l2 + kv; l3 = db * l3 + k;
    base += 3 * HID_;
  }
  size_t S = (size_t)B_ * H_ * NC_ * D_;
  size_t idx = (((size_t)(b * H_ + h)) * NC_ + c) * D_ + d;
  chunkL[idx] = l0; chunkL[S + idx] = l1; chunkL[2 * S + idx] = l2; chunkL[3 * S + idx] = l3;
}

// ---------------- scan phase 3 (scan2 folded in): local prefix + re-scan + emit ------
// Block (b,h,c) recomputes its carry = daC-prefix of chunkL[0..c-1] (4 indep FMA
// chains, coalesced 256B/wave loads), then scans chunk c and writes the bf16
// concat. Block c == NC_-1 also writes the 4 final-state outputs at chunk end.
__global__ __launch_bounds__(64) void k_scan3(const __hip_bfloat16* __restrict__ qkv,
                                              const float* __restrict__ chunkL,
                                              const float* __restrict__ alpha,
                                              const float* __restrict__ beta,
                                              __hip_bfloat16* __restrict__ ocat,
                                              float* __restrict__ out_tail) {
  int blk = blockIdx.x;
  int c = blk & (NC_ - 1), h = (blk >> 6) & (H_ - 1), b = blk >> 10;
  int d = threadIdx.x;
  float da = fmaxf(sigm_(alpha[h]), 1e-8f);
  float db = fmaxf(sigm_(beta[h]), 1e-8f);
  float daC = da, dbC = db;
#pragma unroll
  for (int i = 0; i < 6; ++i) { daC *= daC; dbC *= dbC; }   // d^64
  size_t S = (size_t)B_ * H_ * NC_ * D_;
  size_t cbase = ((size_t)(b * H_ + h)) * NC_ * D_ + d;
  float s0 = 0.f, s1 = 0.f, s2 = 0.f, s3 = 0.f;
  for (int cc = 0; cc < c; ++cc) {                 // carry prefix (exclusive of c)
    size_t idx = cbase + (size_t)cc * D_;
    s0 = daC * s0 + chunkL[idx];
    s1 = daC * s1 + chunkL[S + idx];
    s2 = dbC * s2 + chunkL[2 * S + idx];
    s3 = dbC * s3 + chunkL[3 * S + idx];
  }
  const __hip_bfloat16* base = qkv + (size_t)(b * T_ + c * CCH) * (3 * HID_) + h * D_ + d;
  __hip_bfloat16* ob = ocat + (size_t)(b * T_ + c * CCH) * (2 * HID_) + h * D_ + d;
#pragma unroll 4
  for (int t = 0; t < CCH; ++t) {
    float q = phi_(__bfloat162float(base[0]));
    float k = phi_(__bfloat162float(base[HID_]));
    float v = __bfloat162float(base[2 * HID_]);
    float kv = k * v;
    s0 = da * s0 + kv; s1 = da * s1 + k;
    s2 = db * s2 + kv; s3 = db * s3 + k;
    float pf = q * s1, ps = q * s3;
#pragma unroll
    for (int off = 32; off >= 1; off >>= 1) {
      pf += __shfl_xor(pf, off);
      ps += __shfl_xor(ps, off);
    }
    pf = fmaxf(pf, 1e-6f);
    ps = fmaxf(ps, 1e-6f);
    ob[0]    = __float2bfloat16(q * s0 / pf);
    ob[HID_] = __float2bfloat16(q * s2 / ps);
    base += 3 * HID_;
    ob += 2 * HID_;
  }
  if (c == NC_ - 1) {                              // final states (inclusive of all T)
    int fi = (b * H_ + h) * D_ + d;
    out_tail[fi] = s0;                             // kv_f1
    out_tail[B_ * H_ * D_ + fi] = s1;              // ks_f1
    out_tail[2 * B_ * H_ * D_ + fi] = s2;          // kv_s1
    out_tail[3 * B_ * H_ * D_ + fi] = s3;          // ks_s1
  }
}

extern "C" void kernel_launch(void* const* d_in, const int* in_sizes, int n_in,
                              void* d_out, int out_size, void* d_ws, size_t ws_size,
                              hipStream_t stream) {
  const float* x     = (const float*)d_in[0];
  const float* wqkv  = (const float*)d_in[1];
  const float* wout  = (const float*)d_in[2];
  const float* alpha = (const float*)d_in[3];
  const float* beta  = (const float*)d_in[4];
  float* out = (float*)d_out;

  // ---- workspace layout (~172 MiB) with lifetime aliasing ----
  char* ws = (char*)d_ws;
  __hip_bfloat16* qkv    = (__hip_bfloat16*)(ws);                       // [B*T,3*HID] bf16, 100.7 MB
  char*           reg1   = ws + (size_t)B_ * T_ * 3 * HID_ * 2;         // 67.1 MB shared region:
  __hip_bfloat16* ocat   = (__hip_bfloat16*)reg1;                       //   ocat (live: scan3..GEMM2)
  __hip_bfloat16* xb     = (__hip_bfloat16*)reg1;                       //   xb   (live: prep..GEMM1)
  __hip_bfloat16* wqkvT  = (__hip_bfloat16*)(reg1 + (size_t)B_ * T_ * HID_ * 2); // dies w/ GEMM1
  char*           p2     = reg1 + (size_t)B_ * T_ * 2 * HID_ * 2;
  __hip_bfloat16* woutT  = (__hip_bfloat16*)p2;                         // live to end
  float*          chunkL = (float*)(p2 + (size_t)2 * HID_ * HID_ * 2);
  (void)ws_size; (void)in_sizes; (void)n_in; (void)out_size;

  k_prep<<<NB_CAST + NB_TQ + NB_TO, 256, 0, stream>>>(x, wqkv, wout, xb, wqkvT, woutT);
  k_gemmA<__hip_bfloat16><<<(B_ * T_ / 256) * (3 * HID_ / 256), 512, 0, stream>>>(
      xb, wqkvT, qkv, B_ * T_, 3 * HID_, HID_);
  k_scan1<<<B_ * H_ * NC_, 64, 0, stream>>>(qkv, alpha, beta, chunkL);
  k_scan3<<<B_ * H_ * NC_, 64, 0, stream>>>(qkv, chunkL, alpha, beta, ocat,
                                            out + (size_t)B_ * T_ * HID_);
  k_gemmB<float><<<(B_ * T_ / 256) * (HID_ / 256), 512, 0, stream>>>(
      ocat, woutT, out, B_ * T_, HID_, 2 * HID_);
}

// Round 14
// 259.423 us; speedup vs baseline: 1.0357x; 1.0357x over previous
//
#include <hip/hip_runtime.h>
#include <hip/hip_bf16.h>
#include <stdint.h>

#define B_   4
#define T_   4096
#define HID_ 1024
#define H_   16
#define D_   64
#define CCH  64              // scan chunk length
#define NC_  (T_ / CCH)      // 64 chunks

typedef __attribute__((ext_vector_type(8))) short short8;     // 8 bf16 = 4 VGPRs
typedef __attribute__((ext_vector_type(4))) float f32x4;

__device__ __forceinline__ float phi_(float x) { return x > 0.f ? x + 1.f : __expf(x); }
__device__ __forceinline__ float sigm_(float x) { return 1.f / (1.f + expf(-x)); }

#define BAR() __builtin_amdgcn_s_barrier()
#define PRIO1() __builtin_amdgcn_s_setprio(1)
#define PRIO0() __builtin_amdgcn_s_setprio(0)
#define SCHED0() __builtin_amdgcn_sched_barrier(0)
#define WAITVM0()   { asm volatile("s_waitcnt vmcnt(0)" ::: "memory"); SCHED0(); }
#define WAITVM8()   { asm volatile("s_waitcnt vmcnt(8)" ::: "memory"); SCHED0(); }
#define WAITLGKM0() { asm volatile("s_waitcnt lgkmcnt(0)" ::: "memory"); SCHED0(); }

// ---------------- fused prep: cast x->bf16 (8/thread) + 2 weight transposes ----------
#define NB_CAST (B_ * T_ * HID_ / 2048)                 // 8192
#define NB_TQ   ((3 * HID_ / 32) * (HID_ / 32))         // 3072
#define NB_TO   ((HID_ / 32) * (2 * HID_ / 32))         // 2048
__global__ __launch_bounds__(256) void k_prep(const float* __restrict__ x,
                                              const float* __restrict__ wqkv,
                                              const float* __restrict__ wout,
                                              __hip_bfloat16* __restrict__ xb,
                                              __hip_bfloat16* __restrict__ wqkvT,
                                              __hip_bfloat16* __restrict__ woutT) {
  int bid = blockIdx.x, tid = threadIdx.x;
  if (bid < NB_CAST) {                    // ---- cast: 2048 elems/block
    size_t i = (size_t)bid * 2048 + tid * 8;
    float4 f0 = *(const float4*)(x + i);
    float4 f1 = *(const float4*)(x + i + 4);
    union { short8 v; unsigned short u[8]; } o;
    o.u[0] = __bfloat16_as_ushort(__float2bfloat16(f0.x));
    o.u[1] = __bfloat16_as_ushort(__float2bfloat16(f0.y));
    o.u[2] = __bfloat16_as_ushort(__float2bfloat16(f0.z));
    o.u[3] = __bfloat16_as_ushort(__float2bfloat16(f0.w));
    o.u[4] = __bfloat16_as_ushort(__float2bfloat16(f1.x));
    o.u[5] = __bfloat16_as_ushort(__float2bfloat16(f1.y));
    o.u[6] = __bfloat16_as_ushort(__float2bfloat16(f1.z));
    o.u[7] = __bfloat16_as_ushort(__float2bfloat16(f1.w));
    *(short8*)(xb + i) = o.v;
    return;
  }
  __shared__ float tile[32][33];
  const float* in; __hip_bfloat16* out; int R, C, tb;
  if (bid < NB_CAST + NB_TQ) { in = wqkv; out = wqkvT; R = HID_; C = 3 * HID_; tb = bid - NB_CAST; }
  else                       { in = wout; out = woutT; R = 2 * HID_; C = HID_; tb = bid - NB_CAST - NB_TQ; }
  int nbx = C / 32;
  int c0 = (tb % nbx) * 32, r0 = (tb / nbx) * 32;
  int tx = tid & 31, ty = tid >> 5;        // 32 x 8
#pragma unroll
  for (int i = 0; i < 32; i += 8)
    tile[ty + i][tx] = in[(size_t)(r0 + ty + i) * C + c0 + tx];
  __syncthreads();
#pragma unroll
  for (int i = 0; i < 32; i += 8)
    out[(size_t)(c0 + ty + i) * R + r0 + tx] = __float2bfloat16(tile[tx][ty + i]);
}

// ---------------- async global -> LDS (16B/lane; LDS base wave-uniform) ----------------
__device__ __forceinline__ void gload_lds16(const __hip_bfloat16* g, const __hip_bfloat16* lds) {
  __builtin_amdgcn_global_load_lds(
      (const __attribute__((address_space(1))) uint32_t*)(uintptr_t)g,
      (__attribute__((address_space(3))) uint32_t*)(uintptr_t)lds, 16, 0, 0);
}

// ====================== GEMM variant A (R7, best for GEMM1: K=1024) ==================
template <typename OutT>
__global__ __launch_bounds__(512, 2) void k_gemmA(const __hip_bfloat16* __restrict__ A,
                                                  const __hip_bfloat16* __restrict__ BT,
                                                  OutT* __restrict__ C,
                                                  int M, int N, int K) {
  __shared__ __hip_bfloat16 lds[65536];
  const int tid = threadIdx.x, lane = tid & 63, wid = tid >> 6;
  const int wm = wid >> 2, wn = wid & 3;
  const int r16 = lane & 15, k8 = ((lane >> 4) & 3) * 8;

  const int bid = blockIdx.x;
  const int MT = M >> 8, Rb = MT >> 3;
  const int x = bid & 7, ii = bid >> 3;
  const int rt = x * Rb + (ii % Rb), ct = ii / Rb;
  const int bm = rt << 8, bn = ct << 8;

  const int sRow = wid * 8 + (lane >> 3);
  const int sCol = ((lane & 7) * 8) ^ ((lane >> 3) << 3);
  const __hip_bfloat16* gA = A  + (size_t)(bm + sRow) * K + sCol;
  const __hip_bfloat16* gB = BT + (size_t)(bn + sRow) * K + sCol;

  auto stageA2 = [&](int buf, int kt, int half) {
#pragma unroll
    for (int cc = half * 2; cc < half * 2 + 2; ++cc)
      gload_lds16(gA + (size_t)cc * 64 * K + kt, &lds[buf * 32768 + cc * 4096 + wid * 512]);
  };
  auto stageB2 = [&](int buf, int kt, int half) {
#pragma unroll
    for (int cc = half * 2; cc < half * 2 + 2; ++cc)
      gload_lds16(gB + (size_t)cc * 64 * K + kt, &lds[buf * 32768 + 16384 + cc * 4096 + wid * 512]);
  };
  auto ldA = [&](int buf, int m, int kk) -> short8 {
    int row = wm * 128 + m * 16 + r16;
    int col = (kk * 32 + k8) ^ ((row & 7) << 3);
    return *(const short8*)&lds[buf * 32768 + (row << 6) + col];
  };
  auto ldB = [&](int buf, int n, int kk) -> short8 {
    int row = wn * 64 + n * 16 + r16;
    int col = (kk * 32 + k8) ^ ((row & 7) << 3);
    return *(const short8*)&lds[buf * 32768 + 16384 + (row << 6) + col];
  };

  f32x4 acc[8][4] = {};
  const int NT = K >> 6;

  stageA2(0, 0, 0);  stageA2(0, 0, 1);  stageB2(0, 0, 0);  stageB2(0, 0, 1);
  stageA2(1, 64, 0); stageA2(1, 64, 1); stageB2(1, 64, 0); stageB2(1, 64, 1);
  WAITVM8(); BAR();

  short8 a[8][2], bfr[4][2];
  for (int t = 0; t < NT; ++t) {
    const int cb = t & 1;
    const bool pf = (t + 2 < NT);
    const int kt2 = (t + 2) << 6;
#pragma unroll
    for (int m = 0; m < 8; ++m) { a[m][0] = ldA(cb, m, 0); a[m][1] = ldA(cb, m, 1); }
#pragma unroll
    for (int n = 0; n < 4; ++n) { bfr[n][0] = ldB(cb, n, 0); bfr[n][1] = ldB(cb, n, 1); }
    WAITLGKM0();
    BAR();
    PRIO1();
#pragma unroll
    for (int m = 0; m < 2; ++m)
#pragma unroll
      for (int n = 0; n < 4; ++n) {
        acc[m][n] = __builtin_amdgcn_mfma_f32_16x16x32_bf16(a[m][0], bfr[n][0], acc[m][n], 0, 0, 0);
        acc[m][n] = __builtin_amdgcn_mfma_f32_16x16x32_bf16(a[m][1], bfr[n][1], acc[m][n], 0, 0, 0);
      }
    PRIO0();
    if (pf) stageA2(cb, kt2, 0);
    PRIO1();
#pragma unroll
    for (int m = 2; m < 4; ++m)
#pragma unroll
      for (int n = 0; n < 4; ++n) {
        acc[m][n] = __builtin_amdgcn_mfma_f32_16x16x32_bf16(a[m][0], bfr[n][0], acc[m][n], 0, 0, 0);
        acc[m][n] = __builtin_amdgcn_mfma_f32_16x16x32_bf16(a[m][1], bfr[n][1], acc[m][n], 0, 0, 0);
      }
    PRIO0();
    if (pf) stageA2(cb, kt2, 1);
    PRIO1();
#pragma unroll
    for (int m = 4; m < 6; ++m)
#pragma unroll
      for (int n = 0; n < 4; ++n) {
        acc[m][n] = __builtin_amdgcn_mfma_f32_16x16x32_bf16(a[m][0], bfr[n][0], acc[m][n], 0, 0, 0);
        acc[m][n] = __builtin_amdgcn_mfma_f32_16x16x32_bf16(a[m][1], bfr[n][1], acc[m][n], 0, 0, 0);
      }
    PRIO0();
    if (pf) stageB2(cb, kt2, 0);
    PRIO1();
#pragma unroll
    for (int m = 6; m < 8; ++m)
#pragma unroll
      for (int n = 0; n < 4; ++n) {
        acc[m][n] = __builtin_amdgcn_mfma_f32_16x16x32_bf16(a[m][0], bfr[n][0], acc[m][n], 0, 0, 0);
        acc[m][n] = __builtin_amdgcn_mfma_f32_16x16x32_bf16(a[m][1], bfr[n][1], acc[m][n], 0, 0, 0);
      }
    PRIO0();
    if (pf)              { stageB2(cb, kt2, 1); WAITVM8(); }
    else if (t + 1 < NT) { WAITVM0(); }
    BAR();
  }

#pragma unroll
  for (int m = 0; m < 8; ++m)
#pragma unroll
    for (int n = 0; n < 4; ++n)
#pragma unroll
      for (int j = 0; j < 4; ++j) {
        int row = bm + wm * 128 + m * 16 + ((lane >> 4) << 2) + j;
        int col = bn + wn * 64 + n * 16 + r16;
        if constexpr (sizeof(OutT) == 4)
          C[(size_t)row * N + col] = acc[m][n][j];
        else
          C[(size_t)row * N + col] = __float2bfloat16(acc[m][n][j]);
      }
}

// ====================== GEMM variant B (R8 K-split, best for GEMM2: K=2048) ==========
template <typename OutT>
__global__ __launch_bounds__(512, 2) void k_gemmB(const __hip_bfloat16* __restrict__ A,
                                                  const __hip_bfloat16* __restrict__ BT,
                                                  OutT* __restrict__ C,
                                                  int M, int N, int K) {
  __shared__ __hip_bfloat16 lds[65536];
  const int tid = threadIdx.x, lane = tid & 63, wid = tid >> 6;
  const int wm = wid >> 2, wn = wid & 3;
  const int r16 = lane & 15, k8 = ((lane >> 4) & 3) * 8;

  const int bid = blockIdx.x;
  const int MT = M >> 8, Rb = MT >> 3;
  const int x = bid & 7, ii = bid >> 3;
  const int rt = x * Rb + (ii % Rb), ct = ii / Rb;
  const int bm = rt << 8, bn = ct << 8;

  const int sRow = wid * 8 + (lane >> 3);
  const int sCol = ((lane & 7) * 8) ^ ((lane >> 3) << 3);
  const __hip_bfloat16* gA = A  + (size_t)(bm + sRow) * K + sCol;
  const __hip_bfloat16* gB = BT + (size_t)(bn + sRow) * K + sCol;

  auto stage = [&](int buf, int kt) {
#pragma unroll
    for (int cc = 0; cc < 4; ++cc)
      gload_lds16(gA + (size_t)cc * 64 * K + kt, &lds[buf * 32768 + cc * 4096 + wid * 512]);
#pragma unroll
    for (int cc = 0; cc < 4; ++cc)
      gload_lds16(gB + (size_t)cc * 64 * K + kt, &lds[buf * 32768 + 16384 + cc * 4096 + wid * 512]);
  };
  auto ldA = [&](int buf, int m, int kk) -> short8 {
    int row = wm * 128 + m * 16 + r16;
    int col = (kk * 32 + k8) ^ ((row & 7) << 3);
    return *(const short8*)&lds[buf * 32768 + (row << 6) + col];
  };
  auto ldB = [&](int buf, int n, int kk) -> short8 {
    int row = wn * 64 + n * 16 + r16;
    int col = (kk * 32 + k8) ^ ((row & 7) << 3);
    return *(const short8*)&lds[buf * 32768 + 16384 + (row << 6) + col];
  };

  f32x4 acc[8][4] = {};
  const int NT = K >> 6;

  short8 A0[8], B0[4], A1[8], B1[4];
  stage(0, 0);
  stage(1, 64);
  WAITVM8(); BAR();
#pragma unroll
  for (int m = 0; m < 8; ++m) A0[m] = ldA(0, m, 0);
#pragma unroll
  for (int n = 0; n < 4; ++n) B0[n] = ldB(0, n, 0);
  SCHED0();

  for (int t = 0; t < NT; ++t) {
    const int cb = t & 1;
#pragma unroll
    for (int m = 0; m < 8; ++m) A1[m] = ldA(cb, m, 1);
#pragma unroll
    for (int n = 0; n < 4; ++n) B1[n] = ldB(cb, n, 1);
    SCHED0();
    PRIO1();
#pragma unroll
    for (int m = 0; m < 8; ++m)
#pragma unroll
      for (int n = 0; n < 4; ++n)
        acc[m][n] = __builtin_amdgcn_mfma_f32_16x16x32_bf16(A0[m], B0[n], acc[m][n], 0, 0, 0);
    PRIO0();
    WAITLGKM0();
    BAR();
    if (t + 2 < NT)      { stage(cb, (t + 2) << 6); WAITVM8(); BAR(); }
    else if (t + 1 < NT) { WAITVM0(); BAR(); }
    if (t + 1 < NT) {
#pragma unroll
      for (int m = 0; m < 8; ++m) A0[m] = ldA(cb ^ 1, m, 0);
#pragma unroll
      for (int n = 0; n < 4; ++n) B0[n] = ldB(cb ^ 1, n, 0);
      SCHED0();
    }
    PRIO1();
#pragma unroll
    for (int m = 0; m < 8; ++m)
#pragma unroll
      for (int n = 0; n < 4; ++n)
        acc[m][n] = __builtin_amdgcn_mfma_f32_16x16x32_bf16(A1[m], B1[n], acc[m][n], 0, 0, 0);
    PRIO0();
  }

#pragma unroll
  for (int m = 0; m < 8; ++m)
#pragma unroll
    for (int n = 0; n < 4; ++n)
#pragma unroll
      for (int j = 0; j < 4; ++j) {
        int row = bm + wm * 128 + m * 16 + ((lane >> 4) << 2) + j;
        int col = bn + wn * 64 + n * 16 + r16;
        if constexpr (sizeof(OutT) == 4)
          C[(size_t)row * N + col] = acc[m][n][j];
        else
          C[(size_t)row * N + col] = __float2bfloat16(acc[m][n][j]);
      }
}

// ---------------- scan phase 1: per-chunk local tails (zero init) ----------------
__global__ __launch_bounds__(64) void k_scan1(const __hip_bfloat16* __restrict__ qkv,
                                              const float* __restrict__ alpha,
                                              const float* __restrict__ beta,
                                              float* __restrict__ chunkL) {
  int blk = blockIdx.x;
  int c = blk & (NC_ - 1), h = (blk >> 6) & (H_ - 1), b = blk >> 10;
  int d = threadIdx.x;
  float da = fmaxf(sigm_(alpha[h]), 1e-8f);
  float db = fmaxf(sigm_(beta[h]), 1e-8f);
  const __hip_bfloat16* base = qkv + (size_t)(b * T_ + c * CCH) * (3 * HID_) + h * D_ + d;
  float l0 = 0.f, l1 = 0.f, l2 = 0.f, l3 = 0.f;
#pragma unroll 4
  for (int t = 0; t < CCH; ++t) {
    float k = phi_(__bfloat162float(base[HID_]));
    float v = __bfloat162float(base[2 * HID_]);
    float kv = k * v;
    l0 = da * l0 + kv; l1 = da * l1 + k;
    l2 = db * l2 + kv; l3 = db * l3 + k;
    base += 3 * HID_;
  }
  size_t S = (size_t)B_ * H_ * NC_ * D_;
  size_t idx = (((size_t)(b * H_ + h)) * NC_ + c) * D_ + d;
  chunkL[idx] = l0; chunkL[S + idx] = l1; chunkL[2 * S + idx] = l2; chunkL[3 * S + idx] = l3;
}

// ---------------- scan phase 2: prefix across chunks + final states ----------------
__global__ __launch_bounds__(256) void k_scan2(const float* __restrict__ chunkL,
                                               const float* __restrict__ alpha,
                                               const float* __restrict__ beta,
                                               float* __restrict__ carry,
                                               float* __restrict__ out_tail) {
  int t = blockIdx.x * 256 + threadIdx.x;   // 0..4095 = (b,h,d)
  int d = t & (D_ - 1), h = (t >> 6) & (H_ - 1), b = t >> 10;
  float da = fmaxf(sigm_(alpha[h]), 1e-8f);
  float db = fmaxf(sigm_(beta[h]), 1e-8f);
  float daC = da, dbC = db;
#pragma unroll
  for (int i = 0; i < 6; ++i) { daC *= daC; dbC *= dbC; }   // d^64
  size_t S = (size_t)B_ * H_ * NC_ * D_;
  size_t base = ((size_t)(b * H_ + h)) * NC_ * D_ + d;
  float s0 = 0.f, s1 = 0.f, s2 = 0.f, s3 = 0.f;
  for (int c = 0; c < NC_; ++c) {
    size_t idx = base + (size_t)c * D_;
    carry[idx] = s0; carry[S + idx] = s1; carry[2 * S + idx] = s2; carry[3 * S + idx] = s3;
    s0 = daC * s0 + chunkL[idx];
    s1 = daC * s1 + chunkL[S + idx];
    s2 = dbC * s2 + chunkL[2 * S + idx];
    s3 = dbC * s3 + chunkL[3 * S + idx];
  }
  int fi = (b * H_ + h) * D_ + d;
  out_tail[fi] = s0;                       // kv_f1
  out_tail[B_ * H_ * D_ + fi] = s1;        // ks_f1
  out_tail[2 * B_ * H_ * D_ + fi] = s2;    // kv_s1
  out_tail[3 * B_ * H_ * D_ + fi] = s3;    // ks_s1
}

// ---------------- scan phase 3: re-scan w/ carry, normalize, emit bf16 concat ----------------
__global__ __launch_bounds__(64) void k_scan3(const __hip_bfloat16* __restrict__ qkv,
                                              const float* __restrict__ carry,
                                              const float* __restrict__ alpha,
                                              const float* __restrict__ beta,
                                              __hip_bfloat16* __restrict__ ocat) {
  int blk = blockIdx.x;
  int c = blk & (NC_ - 1), h = (blk >> 6) & (H_ - 1), b = blk >> 10;
  int d = threadIdx.x;
  float da = fmaxf(sigm_(alpha[h]), 1e-8f);
  float db = fmaxf(sigm_(beta[h]), 1e-8f);
  size_t S = (size_t)B_ * H_ * NC_ * D_;
  size_t cidx = (((size_t)(b * H_ + h)) * NC_ + c) * D_ + d;
  float s0 = carry[cidx], s1 = carry[S + cidx], s2 = carry[2 * S + cidx], s3 = carry[3 * S + cidx];
  const __hip_bfloat16* base = qkv + (size_t)(b * T_ + c * CCH) * (3 * HID_) + h * D_ + d;
  __hip_bfloat16* ob = ocat + (size_t)(b * T_ + c * CCH) * (2 * HID_) + h * D_ + d;
#pragma unroll 4
  for (int t = 0; t < CCH; ++t) {
    float q = phi_(__bfloat162float(base[0]));
    float k = phi_(__bfloat162float(base[HID_]));
    float v = __bfloat162float(base[2 * HID_]);
    float kv = k * v;
    s0 = da * s0 + kv; s1 = da * s1 + k;
    s2 = db * s2 + kv; s3 = db * s3 + k;
    float pf = q * s1, ps = q * s3;
#pragma unroll
    for (int off = 32; off >= 1; off >>= 1) {
      pf += __shfl_xor(pf, off);
      ps += __shfl_xor(ps, off);
    }
    pf = fmaxf(pf, 1e-6f);
    ps = fmaxf(ps, 1e-6f);
    ob[0]    = __float2bfloat16(q * s0 / pf);
    ob[HID_] = __float2bfloat16(q * s2 / ps);
    base += 3 * HID_;
    ob += 2 * HID_;
  }
}

extern "C" void kernel_launch(void* const* d_in, const int* in_sizes, int n_in,
                              void* d_out, int out_size, void* d_ws, size_t ws_size,
                              hipStream_t stream) {
  const float* x     = (const float*)d_in[0];
  const float* wqkv  = (const float*)d_in[1];
  const float* wout  = (const float*)d_in[2];
  const float* alpha = (const float*)d_in[3];
  const float* beta  = (const float*)d_in[4];
  float* out = (float*)d_out;

  // ---- workspace layout (~172 MiB) with lifetime aliasing ----
  char* ws = (char*)d_ws;
  __hip_bfloat16* qkv    = (__hip_bfloat16*)(ws);                       // [B*T,3*HID] bf16, 100.7 MB
  char*           reg1   = ws + (size_t)B_ * T_ * 3 * HID_ * 2;         // 67.1 MB shared region:
  __hip_bfloat16* ocat   = (__hip_bfloat16*)reg1;                       //   ocat (live: scan3..GEMM2)
  __hip_bfloat16* xb     = (__hip_bfloat16*)reg1;                       //   xb   (live: prep..GEMM1)
  __hip_bfloat16* wqkvT  = (__hip_bfloat16*)(reg1 + (size_t)B_ * T_ * HID_ * 2); // dies w/ GEMM1
  char*           p2     = reg1 + (size_t)B_ * T_ * 2 * HID_ * 2;
  __hip_bfloat16* woutT  = (__hip_bfloat16*)p2;                         // live to end
  float*          chunkL = (float*)(p2 + (size_t)2 * HID_ * HID_ * 2);
  float*          carry  = (float*)(p2 + (size_t)2 * HID_ * HID_ * 2 + (size_t)4 * B_ * H_ * NC_ * D_ * 4);
  (void)ws_size; (void)in_sizes; (void)n_in; (void)out_size;

  k_prep<<<NB_CAST + NB_TQ + NB_TO, 256, 0, stream>>>(x, wqkv, wout, xb, wqkvT, woutT);
  k_gemmA<__hip_bfloat16><<<(B_ * T_ / 256) * (3 * HID_ / 256), 512, 0, stream>>>(
      xb, wqkvT, qkv, B_ * T_, 3 * HID_, HID_);
  k_scan1<<<B_ * H_ * NC_, 64, 0, stream>>>(qkv, alpha, beta, chunkL);
  k_scan2<<<(B_ * H_ * D_) / 256, 256, 0, stream>>>(chunkL, alpha, beta, carry, out + (size_t)B_ * T_ * HID_);
  k_scan3<<<B_ * H_ * NC_, 64, 0, stream>>>(qkv, carry, alpha, beta, ocat);
  k_gemmB<float><<<(B_ * T_ / 256) * (HID_ / 256), 512, 0, stream>>>(
      ocat, woutT, out, B_ * T_, HID_, 2 * HID_);
}

// Round 15
// 257.864 us; speedup vs baseline: 1.0420x; 1.0060x over previous
//
#include <hip/hip_runtime.h>
#include <hip/hip_bf16.h>
#include <stdint.h>

#define B_   4
#define T_   4096
#define HID_ 1024
#define H_   16
#define D_   64
#define CCH  64              // scan chunk length
#define NC_  (T_ / CCH)      // 64 chunks

typedef __attribute__((ext_vector_type(8))) short short8;     // 8 bf16 = 4 VGPRs
typedef __attribute__((ext_vector_type(4))) float f32x4;

__device__ __forceinline__ float phi_(float x) { return x > 0.f ? x + 1.f : __expf(x); }
__device__ __forceinline__ float sigm_(float x) { return 1.f / (1.f + expf(-x)); }

#define BAR() __builtin_amdgcn_s_barrier()
#define PRIO1() __builtin_amdgcn_s_setprio(1)
#define PRIO0() __builtin_amdgcn_s_setprio(0)
#define SCHED0() __builtin_amdgcn_sched_barrier(0)
#define WAITVM0()   { asm volatile("s_waitcnt vmcnt(0)" ::: "memory"); SCHED0(); }
#define WAITVM8()   { asm volatile("s_waitcnt vmcnt(8)" ::: "memory"); SCHED0(); }
#define WAITLGKM0() { asm volatile("s_waitcnt lgkmcnt(0)" ::: "memory"); SCHED0(); }

// ---------------- fused prep: cast x->bf16 (8/thread) + 2 weight transposes ----------
#define NB_CAST (B_ * T_ * HID_ / 2048)                 // 8192
#define NB_TQ   ((3 * HID_ / 32) * (HID_ / 32))         // 3072
#define NB_TO   ((HID_ / 32) * (2 * HID_ / 32))         // 2048
__global__ __launch_bounds__(256) void k_prep(const float* __restrict__ x,
                                              const float* __restrict__ wqkv,
                                              const float* __restrict__ wout,
                                              __hip_bfloat16* __restrict__ xb,
                                              __hip_bfloat16* __restrict__ wqkvT,
                                              __hip_bfloat16* __restrict__ woutT) {
  int bid = blockIdx.x, tid = threadIdx.x;
  if (bid < NB_CAST) {                    // ---- cast: 2048 elems/block
    size_t i = (size_t)bid * 2048 + tid * 8;
    float4 f0 = *(const float4*)(x + i);
    float4 f1 = *(const float4*)(x + i + 4);
    union { short8 v; unsigned short u[8]; } o;
    o.u[0] = __bfloat16_as_ushort(__float2bfloat16(f0.x));
    o.u[1] = __bfloat16_as_ushort(__float2bfloat16(f0.y));
    o.u[2] = __bfloat16_as_ushort(__float2bfloat16(f0.z));
    o.u[3] = __bfloat16_as_ushort(__float2bfloat16(f0.w));
    o.u[4] = __bfloat16_as_ushort(__float2bfloat16(f1.x));
    o.u[5] = __bfloat16_as_ushort(__float2bfloat16(f1.y));
    o.u[6] = __bfloat16_as_ushort(__float2bfloat16(f1.z));
    o.u[7] = __bfloat16_as_ushort(__float2bfloat16(f1.w));
    *(short8*)(xb + i) = o.v;
    return;
  }
  __shared__ float tile[32][33];
  const float* in; __hip_bfloat16* out; int R, C, tb;
  if (bid < NB_CAST + NB_TQ) { in = wqkv; out = wqkvT; R = HID_; C = 3 * HID_; tb = bid - NB_CAST; }
  else                       { in = wout; out = woutT; R = 2 * HID_; C = HID_; tb = bid - NB_CAST - NB_TQ; }
  int nbx = C / 32;
  int c0 = (tb % nbx) * 32, r0 = (tb / nbx) * 32;
  int tx = tid & 31, ty = tid >> 5;        // 32 x 8
#pragma unroll
  for (int i = 0; i < 32; i += 8)
    tile[ty + i][tx] = in[(size_t)(r0 + ty + i) * C + c0 + tx];
  __syncthreads();
#pragma unroll
  for (int i = 0; i < 32; i += 8)
    out[(size_t)(c0 + ty + i) * R + r0 + tx] = __float2bfloat16(tile[tx][ty + i]);
}

// ---------------- async global -> LDS (16B/lane; LDS base wave-uniform) ----------------
__device__ __forceinline__ void gload_lds16(const __hip_bfloat16* g, const __hip_bfloat16* lds) {
  __builtin_amdgcn_global_load_lds(
      (const __attribute__((address_space(1))) uint32_t*)(uintptr_t)g,
      (__attribute__((address_space(3))) uint32_t*)(uintptr_t)lds, 16, 0, 0);
}

// ====================== GEMM variant A (R7, best for GEMM1: K=1024) ==================
// Measured: 118 us, MfmaUtil ~36%, 0 bank conflicts, FETCH 74 MB -- at the
// plain-HIP structural ceiling (6 schedule variants converged here, R4-R11).
template <typename OutT>
__global__ __launch_bounds__(512, 2) void k_gemmA(const __hip_bfloat16* __restrict__ A,
                                                  const __hip_bfloat16* __restrict__ BT,
                                                  OutT* __restrict__ C,
                                                  int M, int N, int K) {
  __shared__ __hip_bfloat16 lds[65536];
  const int tid = threadIdx.x, lane = tid & 63, wid = tid >> 6;
  const int wm = wid >> 2, wn = wid & 3;
  const int r16 = lane & 15, k8 = ((lane >> 4) & 3) * 8;

  const int bid = blockIdx.x;
  const int MT = M >> 8, Rb = MT >> 3;
  const int x = bid & 7, ii = bid >> 3;
  const int rt = x * Rb + (ii % Rb), ct = ii / Rb;
  const int bm = rt << 8, bn = ct << 8;

  const int sRow = wid * 8 + (lane >> 3);
  const int sCol = ((lane & 7) * 8) ^ ((lane >> 3) << 3);
  const __hip_bfloat16* gA = A  + (size_t)(bm + sRow) * K + sCol;
  const __hip_bfloat16* gB = BT + (size_t)(bn + sRow) * K + sCol;

  auto stageA2 = [&](int buf, int kt, int half) {
#pragma unroll
    for (int cc = half * 2; cc < half * 2 + 2; ++cc)
      gload_lds16(gA + (size_t)cc * 64 * K + kt, &lds[buf * 32768 + cc * 4096 + wid * 512]);
  };
  auto stageB2 = [&](int buf, int kt, int half) {
#pragma unroll
    for (int cc = half * 2; cc < half * 2 + 2; ++cc)
      gload_lds16(gB + (size_t)cc * 64 * K + kt, &lds[buf * 32768 + 16384 + cc * 4096 + wid * 512]);
  };
  auto ldA = [&](int buf, int m, int kk) -> short8 {
    int row = wm * 128 + m * 16 + r16;
    int col = (kk * 32 + k8) ^ ((row & 7) << 3);
    return *(const short8*)&lds[buf * 32768 + (row << 6) + col];
  };
  auto ldB = [&](int buf, int n, int kk) -> short8 {
    int row = wn * 64 + n * 16 + r16;
    int col = (kk * 32 + k8) ^ ((row & 7) << 3);
    return *(const short8*)&lds[buf * 32768 + 16384 + (row << 6) + col];
  };

  f32x4 acc[8][4] = {};
  const int NT = K >> 6;

  stageA2(0, 0, 0);  stageA2(0, 0, 1);  stageB2(0, 0, 0);  stageB2(0, 0, 1);
  stageA2(1, 64, 0); stageA2(1, 64, 1); stageB2(1, 64, 0); stageB2(1, 64, 1);
  WAITVM8(); BAR();

  short8 a[8][2], bfr[4][2];
  for (int t = 0; t < NT; ++t) {
    const int cb = t & 1;
    const bool pf = (t + 2 < NT);
    const int kt2 = (t + 2) << 6;
#pragma unroll
    for (int m = 0; m < 8; ++m) { a[m][0] = ldA(cb, m, 0); a[m][1] = ldA(cb, m, 1); }
#pragma unroll
    for (int n = 0; n < 4; ++n) { bfr[n][0] = ldB(cb, n, 0); bfr[n][1] = ldB(cb, n, 1); }
    WAITLGKM0();
    BAR();
    PRIO1();
#pragma unroll
    for (int m = 0; m < 2; ++m)
#pragma unroll
      for (int n = 0; n < 4; ++n) {
        acc[m][n] = __builtin_amdgcn_mfma_f32_16x16x32_bf16(a[m][0], bfr[n][0], acc[m][n], 0, 0, 0);
        acc[m][n] = __builtin_amdgcn_mfma_f32_16x16x32_bf16(a[m][1], bfr[n][1], acc[m][n], 0, 0, 0);
      }
    PRIO0();
    if (pf) stageA2(cb, kt2, 0);
    PRIO1();
#pragma unroll
    for (int m = 2; m < 4; ++m)
#pragma unroll
      for (int n = 0; n < 4; ++n) {
        acc[m][n] = __builtin_amdgcn_mfma_f32_16x16x32_bf16(a[m][0], bfr[n][0], acc[m][n], 0, 0, 0);
        acc[m][n] = __builtin_amdgcn_mfma_f32_16x16x32_bf16(a[m][1], bfr[n][1], acc[m][n], 0, 0, 0);
      }
    PRIO0();
    if (pf) stageA2(cb, kt2, 1);
    PRIO1();
#pragma unroll
    for (int m = 4; m < 6; ++m)
#pragma unroll
      for (int n = 0; n < 4; ++n) {
        acc[m][n] = __builtin_amdgcn_mfma_f32_16x16x32_bf16(a[m][0], bfr[n][0], acc[m][n], 0, 0, 0);
        acc[m][n] = __builtin_amdgcn_mfma_f32_16x16x32_bf16(a[m][1], bfr[n][1], acc[m][n], 0, 0, 0);
      }
    PRIO0();
    if (pf) stageB2(cb, kt2, 0);
    PRIO1();
#pragma unroll
    for (int m = 6; m < 8; ++m)
#pragma unroll
      for (int n = 0; n < 4; ++n) {
        acc[m][n] = __builtin_amdgcn_mfma_f32_16x16x32_bf16(a[m][0], bfr[n][0], acc[m][n], 0, 0, 0);
        acc[m][n] = __builtin_amdgcn_mfma_f32_16x16x32_bf16(a[m][1], bfr[n][1], acc[m][n], 0, 0, 0);
      }
    PRIO0();
    if (pf)              { stageB2(cb, kt2, 1); WAITVM8(); }
    else if (t + 1 < NT) { WAITVM0(); }
    BAR();
  }

#pragma unroll
  for (int m = 0; m < 8; ++m)
#pragma unroll
    for (int n = 0; n < 4; ++n)
#pragma unroll
      for (int j = 0; j < 4; ++j) {
        int row = bm + wm * 128 + m * 16 + ((lane >> 4) << 2) + j;
        int col = bn + wn * 64 + n * 16 + r16;
        if constexpr (sizeof(OutT) == 4)
          C[(size_t)row * N + col] = acc[m][n][j];
        else
          C[(size_t)row * N + col] = __float2bfloat16(acc[m][n][j]);
      }
}

// ====================== GEMM variant B (R8 K-split, best for GEMM2: K=2048) ==========
template <typename OutT>
__global__ __launch_bounds__(512, 2) void k_gemmB(const __hip_bfloat16* __restrict__ A,
                                                  const __hip_bfloat16* __restrict__ BT,
                                                  OutT* __restrict__ C,
                                                  int M, int N, int K) {
  __shared__ __hip_bfloat16 lds[65536];
  const int tid = threadIdx.x, lane = tid & 63, wid = tid >> 6;
  const int wm = wid >> 2, wn = wid & 3;
  const int r16 = lane & 15, k8 = ((lane >> 4) & 3) * 8;

  const int bid = blockIdx.x;
  const int MT = M >> 8, Rb = MT >> 3;
  const int x = bid & 7, ii = bid >> 3;
  const int rt = x * Rb + (ii % Rb), ct = ii / Rb;
  const int bm = rt << 8, bn = ct << 8;

  const int sRow = wid * 8 + (lane >> 3);
  const int sCol = ((lane & 7) * 8) ^ ((lane >> 3) << 3);
  const __hip_bfloat16* gA = A  + (size_t)(bm + sRow) * K + sCol;
  const __hip_bfloat16* gB = BT + (size_t)(bn + sRow) * K + sCol;

  auto stage = [&](int buf, int kt) {
#pragma unroll
    for (int cc = 0; cc < 4; ++cc)
      gload_lds16(gA + (size_t)cc * 64 * K + kt, &lds[buf * 32768 + cc * 4096 + wid * 512]);
#pragma unroll
    for (int cc = 0; cc < 4; ++cc)
      gload_lds16(gB + (size_t)cc * 64 * K + kt, &lds[buf * 32768 + 16384 + cc * 4096 + wid * 512]);
  };
  auto ldA = [&](int buf, int m, int kk) -> short8 {
    int row = wm * 128 + m * 16 + r16;
    int col = (kk * 32 + k8) ^ ((row & 7) << 3);
    return *(const short8*)&lds[buf * 32768 + (row << 6) + col];
  };
  auto ldB = [&](int buf, int n, int kk) -> short8 {
    int row = wn * 64 + n * 16 + r16;
    int col = (kk * 32 + k8) ^ ((row & 7) << 3);
    return *(const short8*)&lds[buf * 32768 + 16384 + (row << 6) + col];
  };

  f32x4 acc[8][4] = {};
  const int NT = K >> 6;

  short8 A0[8], B0[4], A1[8], B1[4];
  stage(0, 0);
  stage(1, 64);
  WAITVM8(); BAR();
#pragma unroll
  for (int m = 0; m < 8; ++m) A0[m] = ldA(0, m, 0);
#pragma unroll
  for (int n = 0; n < 4; ++n) B0[n] = ldB(0, n, 0);
  SCHED0();

  for (int t = 0; t < NT; ++t) {
    const int cb = t & 1;
#pragma unroll
    for (int m = 0; m < 8; ++m) A1[m] = ldA(cb, m, 1);
#pragma unroll
    for (int n = 0; n < 4; ++n) B1[n] = ldB(cb, n, 1);
    SCHED0();
    PRIO1();
#pragma unroll
    for (int m = 0; m < 8; ++m)
#pragma unroll
      for (int n = 0; n < 4; ++n)
        acc[m][n] = __builtin_amdgcn_mfma_f32_16x16x32_bf16(A0[m], B0[n], acc[m][n], 0, 0, 0);
    PRIO0();
    WAITLGKM0();
    BAR();
    if (t + 2 < NT)      { stage(cb, (t + 2) << 6); WAITVM8(); BAR(); }
    else if (t + 1 < NT) { WAITVM0(); BAR(); }
    if (t + 1 < NT) {
#pragma unroll
      for (int m = 0; m < 8; ++m) A0[m] = ldA(cb ^ 1, m, 0);
#pragma unroll
      for (int n = 0; n < 4; ++n) B0[n] = ldB(cb ^ 1, n, 0);
      SCHED0();
    }
    PRIO1();
#pragma unroll
    for (int m = 0; m < 8; ++m)
#pragma unroll
      for (int n = 0; n < 4; ++n)
        acc[m][n] = __builtin_amdgcn_mfma_f32_16x16x32_bf16(A1[m], B1[n], acc[m][n], 0, 0, 0);
    PRIO0();
  }

#pragma unroll
  for (int m = 0; m < 8; ++m)
#pragma unroll
    for (int n = 0; n < 4; ++n)
#pragma unroll
      for (int j = 0; j < 4; ++j) {
        int row = bm + wm * 128 + m * 16 + ((lane >> 4) << 2) + j;
        int col = bn + wn * 64 + n * 16 + r16;
        if constexpr (sizeof(OutT) == 4)
          C[(size_t)row * N + col] = acc[m][n][j];
        else
          C[(size_t)row * N + col] = __float2bfloat16(acc[m][n][j]);
      }
}

// ---------------- scan phase 1: per-chunk local tails (zero init) ----------------
__global__ __launch_bounds__(64) void k_scan1(const __hip_bfloat16* __restrict__ qkv,
                                              const float* __restrict__ alpha,
                                              const float* __restrict__ beta,
                                              float* __restrict__ chunkL) {
  int blk = blockIdx.x;
  int c = blk & (NC_ - 1), h = (blk >> 6) & (H_ - 1), b = blk >> 10;
  int d = threadIdx.x;
  float da = fmaxf(sigm_(alpha[h]), 1e-8f);
  float db = fmaxf(sigm_(beta[h]), 1e-8f);
  const __hip_bfloat16* base = qkv + (size_t)(b * T_ + c * CCH) * (3 * HID_) + h * D_ + d;
  float l0 = 0.f, l1 = 0.f, l2 = 0.f, l3 = 0.f;
#pragma unroll 4
  for (int t = 0; t < CCH; ++t) {
    float k = phi_(__bfloat162float(base[HID_]));
    float v = __bfloat162float(base[2 * HID_]);
    float kv = k * v;
    l0 = da * l0 + kv; l1 = da * l1 + k;
    l2 = db * l2 + kv; l3 = db * l3 + k;
    base += 3 * HID_;
  }
  size_t S = (size_t)B_ * H_ * NC_ * D_;
  size_t idx = (((size_t)(b * H_ + h)) * NC_ + c) * D_ + d;
  chunkL[idx] = l0; chunkL[S + idx] = l1; chunkL[2 * S + idx] = l2; chunkL[3 * S + idx] = l3;
}

// ---------------- scan phase 2: prefix across chunks + final states ----------------
__global__ __launch_bounds__(256) void k_scan2(const float* __restrict__ chunkL,
                                               const float* __restrict__ alpha,
                                               const float* __restrict__ beta,
                                               float* __restrict__ carry,
                                               float* __restrict__ out_tail) {
  int t = blockIdx.x * 256 + threadIdx.x;   // 0..4095 = (b,h,d)
  int d = t & (D_ - 1), h = (t >> 6) & (H_ - 1), b = t >> 10;
  float da = fmaxf(sigm_(alpha[h]), 1e-8f);
  float db = fmaxf(sigm_(beta[h]), 1e-8f);
  float daC = da, dbC = db;
#pragma unroll
  for (int i = 0; i < 6; ++i) { daC *= daC; dbC *= dbC; }   // d^64
  size_t S = (size_t)B_ * H_ * NC_ * D_;
  size_t base = ((size_t)(b * H_ + h)) * NC_ * D_ + d;
  float s0 = 0.f, s1 = 0.f, s2 = 0.f, s3 = 0.f;
  for (int c = 0; c < NC_; ++c) {
    size_t idx = base + (size_t)c * D_;
    carry[idx] = s0; carry[S + idx] = s1; carry[2 * S + idx] = s2; carry[3 * S + idx] = s3;
    s0 = daC * s0 + chunkL[idx];
    s1 = daC * s1 + chunkL[S + idx];
    s2 = dbC * s2 + chunkL[2 * S + idx];
    s3 = dbC * s3 + chunkL[3 * S + idx];
  }
  int fi = (b * H_ + h) * D_ + d;
  out_tail[fi] = s0;                       // kv_f1
  out_tail[B_ * H_ * D_ + fi] = s1;        // ks_f1
  out_tail[2 * B_ * H_ * D_ + fi] = s2;    // kv_s1
  out_tail[3 * B_ * H_ * D_ + fi] = s3;    // ks_s1
}

// ---------------- scan phase 3: re-scan w/ carry, normalize, emit bf16 concat ----------------
__global__ __launch_bounds__(64) void k_scan3(const __hip_bfloat16* __restrict__ qkv,
                                              const float* __restrict__ carry,
                                              const float* __restrict__ alpha,
                                              const float* __restrict__ beta,
                                              __hip_bfloat16* __restrict__ ocat) {
  int blk = blockIdx.x;
  int c = blk & (NC_ - 1), h = (blk >> 6) & (H_ - 1), b = blk >> 10;
  int d = threadIdx.x;
  float da = fmaxf(sigm_(alpha[h]), 1e-8f);
  float db = fmaxf(sigm_(beta[h]), 1e-8f);
  size_t S = (size_t)B_ * H_ * NC_ * D_;
  size_t cidx = (((size_t)(b * H_ + h)) * NC_ + c) * D_ + d;
  float s0 = carry[cidx], s1 = carry[S + cidx], s2 = carry[2 * S + cidx], s3 = carry[3 * S + cidx];
  const __hip_bfloat16* base = qkv + (size_t)(b * T_ + c * CCH) * (3 * HID_) + h * D_ + d;
  __hip_bfloat16* ob = ocat + (size_t)(b * T_ + c * CCH) * (2 * HID_) + h * D_ + d;
#pragma unroll 4
  for (int t = 0; t < CCH; ++t) {
    float q = phi_(__bfloat162float(base[0]));
    float k = phi_(__bfloat162float(base[HID_]));
    float v = __bfloat162float(base[2 * HID_]);
    float kv = k * v;
    s0 = da * s0 + kv; s1 = da * s1 + k;
    s2 = db * s2 + kv; s3 = db * s3 + k;
    float pf = q * s1, ps = q * s3;
#pragma unroll
    for (int off = 32; off >= 1; off >>= 1) {
      pf += __shfl_xor(pf, off);
      ps += __shfl_xor(ps, off);
    }
    pf = fmaxf(pf, 1e-6f);
    ps = fmaxf(ps, 1e-6f);
    ob[0]    = __float2bfloat16(q * s0 / pf);
    ob[HID_] = __float2bfloat16(q * s2 / ps);
    base += 3 * HID_;
    ob += 2 * HID_;
  }
}

extern "C" void kernel_launch(void* const* d_in, const int* in_sizes, int n_in,
                              void* d_out, int out_size, void* d_ws, size_t ws_size,
                              hipStream_t stream) {
  const float* x     = (const float*)d_in[0];
  const float* wqkv  = (const float*)d_in[1];
  const float* wout  = (const float*)d_in[2];
  const float* alpha = (const float*)d_in[3];
  const float* beta  = (const float*)d_in[4];
  float* out = (float*)d_out;

  // ---- workspace layout (~172 MiB) with lifetime aliasing ----
  char* ws = (char*)d_ws;
  __hip_bfloat16* qkv    = (__hip_bfloat16*)(ws);                       // [B*T,3*HID] bf16, 100.7 MB
  char*           reg1   = ws + (size_t)B_ * T_ * 3 * HID_ * 2;         // 67.1 MB shared region:
  __hip_bfloat16* ocat   = (__hip_bfloat16*)reg1;                       //   ocat (live: scan3..GEMM2)
  __hip_bfloat16* xb     = (__hip_bfloat16*)reg1;                       //   xb   (live: prep..GEMM1)
  __hip_bfloat16* wqkvT  = (__hip_bfloat16*)(reg1 + (size_t)B_ * T_ * HID_ * 2); // dies w/ GEMM1
  char*           p2     = reg1 + (size_t)B_ * T_ * 2 * HID_ * 2;
  __hip_bfloat16* woutT  = (__hip_bfloat16*)p2;                         // live to end
  float*          chunkL = (float*)(p2 + (size_t)2 * HID_ * HID_ * 2);
  float*          carry  = (float*)(p2 + (size_t)2 * HID_ * HID_ * 2 + (size_t)4 * B_ * H_ * NC_ * D_ * 4);
  (void)ws_size; (void)in_sizes; (void)n_in; (void)out_size;

  k_prep<<<NB_CAST + NB_TQ + NB_TO, 256, 0, stream>>>(x, wqkv, wout, xb, wqkvT, woutT);
  k_gemmA<__hip_bfloat16><<<(B_ * T_ / 256) * (3 * HID_ / 256), 512, 0, stream>>>(
      xb, wqkvT, qkv, B_ * T_, 3 * HID_, HID_);
  k_scan1<<<B_ * H_ * NC_, 64, 0, stream>>>(qkv, alpha, beta, chunkL);
  k_scan2<<<(B_ * H_ * D_) / 256, 256, 0, stream>>>(chunkL, alpha, beta, carry, out + (size_t)B_ * T_ * HID_);
  k_scan3<<<B_ * H_ * NC_, 64, 0, stream>>>(qkv, carry, alpha, beta, ocat);
  k_gemmB<float><<<(B_ * T_ / 256) * (HID_ / 256), 512, 0, stream>>>(
      ocat, woutT, out, B_ * T_, HID_, 2 * HID_);
}